// Round 1
// baseline (1255.117 us; speedup 1.0000x reference)
//
#include <hip/hip_runtime.h>
#include <hip/hip_bf16.h>
#include <math.h>

// ---------------------------------------------------------------------------
// GAT 2-layer forward, fp32.
// Per layer:
//   1) h = x @ W^T              [N, 128]  (H=2 heads * C=64 contiguous)
//   2) s_i[n,h] = dot(h[n,h,:], att[h,:C]); s_j[n,h] = dot(h[n,h,:], att[h,C:])
//   3) per edge e (src,dst): a = leaky(s_i[dst]+s_j[src]); e_a = exp(a);
//      Z[h] = sum_e e_a   (global softmax denominator; max-shift skipped —
//      logits bounded ~|2|, mathematically identical)
//   4) aggr[dst] += (e_a/Z) * h[src]   (atomic f32)
//   5) out = mean over heads + bias (+ relu for layer 1)
// ---------------------------------------------------------------------------

#define WS_F(p) ((float*)(p))

// h[n, c] = sum_k x[n,k] * W[c,k],  c in [0,128)
template <int FIN>
__global__ __launch_bounds__(256) void gemm_nodes(
    const float* __restrict__ x, const float* __restrict__ W,
    float* __restrict__ h, int N) {
  const int NB = 64;
  __shared__ float xs[NB * FIN];
  int ntiles = (N + NB - 1) / NB;
  for (int tile = blockIdx.x; tile < ntiles; tile += gridDim.x) {
    int n0 = tile * NB;
    int cnt = min(NB, N - n0);
    __syncthreads();  // previous tile consumers done
    int nf4 = cnt * FIN / 4;
    const float4* xg4 = (const float4*)(x + (size_t)n0 * FIN);
    for (int i = threadIdx.x; i < nf4; i += 256) ((float4*)xs)[i] = xg4[i];
    __syncthreads();
    int col = threadIdx.x & 127;
    const float4* W4 = (const float4*)(W + (size_t)col * FIN);
    for (int nn = (threadIdx.x >> 7); nn < cnt; nn += 2) {
      const float4* xs4 = (const float4*)(xs + nn * FIN);
      float acc = 0.f;
#pragma unroll
      for (int k = 0; k < FIN / 4; ++k) {
        float4 w = W4[k];
        float4 xv = xs4[k];
        acc += w.x * xv.x + w.y * xv.y + w.z * xv.z + w.w * xv.w;
      }
      h[(size_t)(n0 + nn) * 128 + col] = acc;
    }
  }
}

// one wave per (node, head): s_i, s_j dot products
__global__ __launch_bounds__(256) void node_scores(
    const float* __restrict__ h, const float* __restrict__ att,
    float* __restrict__ si, float* __restrict__ sj, int N) {
  int lane = threadIdx.x & 63;
  int wid = (blockIdx.x * blockDim.x + threadIdx.x) >> 6;
  int nw = (gridDim.x * blockDim.x) >> 6;
  for (int t = wid; t < N * 2; t += nw) {
    int n = t >> 1, hd = t & 1;
    float p = h[(size_t)n * 128 + hd * 64 + lane];
    float vi = p * att[hd * 128 + lane];
    float vj = p * att[hd * 128 + 64 + lane];
#pragma unroll
    for (int off = 32; off; off >>= 1) {
      vi += __shfl_down(vi, off, 64);
      vj += __shfl_down(vj, off, 64);
    }
    if (lane == 0) { si[t] = vi; sj[t] = vj; }
  }
}

// per-edge: alpha = exp(leaky(s_i[dst]+s_j[src])), store; accumulate Z[h]
__global__ __launch_bounds__(256) void edge_exp_sum(
    const int* __restrict__ srcE, const int* __restrict__ dstE,
    const float* __restrict__ si, const float* __restrict__ sj,
    float* __restrict__ ab, float* __restrict__ Z, int E, int Etot) {
  float s0 = 0.f, s1 = 0.f;
  int tid = blockIdx.x * blockDim.x + threadIdx.x;
  int stride = gridDim.x * blockDim.x;
  for (int e = tid; e < Etot; e += stride) {
    int s, d;
    if (e < E) { s = srcE[e]; d = dstE[e]; } else { s = d = e - E; }
    float a0 = si[d * 2] + sj[s * 2];
    float a1 = si[d * 2 + 1] + sj[s * 2 + 1];
    a0 = a0 >= 0.f ? a0 : 0.2f * a0;
    a1 = a1 >= 0.f ? a1 : 0.2f * a1;
    float e0 = __expf(a0), e1 = __expf(a1);
    ab[(size_t)e * 2] = e0;
    ab[(size_t)e * 2 + 1] = e1;
    s0 += e0; s1 += e1;
  }
  __shared__ float r0[4], r1[4];
  int lane = threadIdx.x & 63, w = threadIdx.x >> 6;
#pragma unroll
  for (int off = 32; off; off >>= 1) {
    s0 += __shfl_down(s0, off, 64);
    s1 += __shfl_down(s1, off, 64);
  }
  if (lane == 0) { r0[w] = s0; r1[w] = s1; }
  __syncthreads();
  if (threadIdx.x == 0) {
    atomicAdd(&Z[0], r0[0] + r0[1] + r0[2] + r0[3]);
    atomicAdd(&Z[1], r1[0] + r1[1] + r1[2] + r1[3]);
  }
}

// one wave per edge: aggr[dst] += (alpha/Z) * h[src]
__global__ __launch_bounds__(256) void edge_aggregate(
    const int* __restrict__ srcE, const int* __restrict__ dstE,
    const float* __restrict__ h, const float* __restrict__ ab,
    const float* __restrict__ Z, float* __restrict__ aggr, int E, int Etot) {
  int lane = threadIdx.x & 63;
  int wid = (blockIdx.x * blockDim.x + threadIdx.x) >> 6;
  int nw = (gridDim.x * blockDim.x) >> 6;
  float z0 = 1.f / (Z[0] + 1e-10f);
  float z1 = 1.f / (Z[1] + 1e-10f);
  for (int e = wid; e < Etot; e += nw) {
    int s, d;
    if (e < E) { s = srcE[e]; d = dstE[e]; } else { s = d = e - E; }
    float w0 = ab[(size_t)e * 2] * z0;
    float w1 = ab[(size_t)e * 2 + 1] * z1;
    float v0 = h[(size_t)s * 128 + lane];
    float v1 = h[(size_t)s * 128 + 64 + lane];
    unsafeAtomicAdd(&aggr[(size_t)d * 128 + lane], v0 * w0);
    unsafeAtomicAdd(&aggr[(size_t)d * 128 + 64 + lane], v1 * w1);
  }
}

// out[n,c] = mean_h aggr[n,h,c] + bias[c]  (+relu)
__global__ __launch_bounds__(256) void finalize(
    const float* __restrict__ aggr, const float* __restrict__ bias,
    float* __restrict__ out, int N, int do_relu) {
  int i = blockIdx.x * blockDim.x + threadIdx.x;
  if (i >= N * 64) return;
  int n = i >> 6, c = i & 63;
  float v = 0.5f * (aggr[(size_t)n * 128 + c] + aggr[(size_t)n * 128 + 64 + c]) + bias[c];
  if (do_relu) v = fmaxf(v, 0.f);
  out[i] = v;
}

extern "C" void kernel_launch(void* const* d_in, const int* in_sizes, int n_in,
                              void* d_out, int out_size, void* d_ws, size_t ws_size,
                              hipStream_t stream) {
  const float* x    = (const float*)d_in[0];
  const int*   ei   = (const int*)d_in[1];   // [2, E] int32 per harness doc
  const float* W1   = (const float*)d_in[2];
  const float* att1 = (const float*)d_in[3];
  const float* b1   = (const float*)d_in[4];
  const float* W2   = (const float*)d_in[5];
  const float* att2 = (const float*)d_in[6];
  const float* b2   = (const float*)d_in[7];
  float* out = (float*)d_out;

  const int N = in_sizes[0] / 128;   // 50000
  const int E = in_sizes[1] / 2;     // 800000
  const int Etot = E + N;
  const int* srcE = ei;
  const int* dstE = ei + E;

  // workspace layout (floats), all float4-aligned
  float* h    = WS_F(d_ws);            // N*128
  float* si   = h + (size_t)N * 128;   // N*2
  float* sj   = si + (size_t)N * 2;    // N*2
  float* ab   = sj + (size_t)N * 2;    // Etot*2
  float* Z    = ab + (size_t)Etot * 2; // 4
  float* aggr = Z + 4;                 // N*128
  float* x2   = aggr + (size_t)N * 128; // N*64

  dim3 blk(256);

  // ---------------- layer 1 ----------------
  gemm_nodes<128><<<512, blk, 0, stream>>>(x, W1, h, N);
  node_scores<<<1024, blk, 0, stream>>>(h, att1, si, sj, N);
  hipMemsetAsync(Z, 0, 16, stream);
  edge_exp_sum<<<1024, blk, 0, stream>>>(srcE, dstE, si, sj, ab, Z, E, Etot);
  hipMemsetAsync(aggr, 0, (size_t)N * 128 * sizeof(float), stream);
  edge_aggregate<<<2048, blk, 0, stream>>>(srcE, dstE, h, ab, Z, aggr, E, Etot);
  finalize<<<(N * 64 + 255) / 256, blk, 0, stream>>>(aggr, b1, x2, N, 1);

  // ---------------- layer 2 ----------------
  gemm_nodes<64><<<512, blk, 0, stream>>>(x2, W2, h, N);
  node_scores<<<1024, blk, 0, stream>>>(h, att2, si, sj, N);
  hipMemsetAsync(Z, 0, 16, stream);
  edge_exp_sum<<<1024, blk, 0, stream>>>(srcE, dstE, si, sj, ab, Z, E, Etot);
  hipMemsetAsync(aggr, 0, (size_t)N * 128 * sizeof(float), stream);
  edge_aggregate<<<2048, blk, 0, stream>>>(srcE, dstE, h, ab, Z, aggr, E, Etot);
  finalize<<<(N * 64 + 255) / 256, blk, 0, stream>>>(aggr, b2, out, N, 0);
}

// Round 2
// 669.313 us; speedup vs baseline: 1.8752x; 1.8752x over previous
//
#include <hip/hip_runtime.h>
#include <hip/hip_bf16.h>
#include <math.h>

// ---------------------------------------------------------------------------
// GAT 2-layer forward, fp32, CSR-based aggregation (no f32 atomics).
//
// Once per call:  counting-sort edges by dst -> rowptr[N+1], esrc[Etot]
// Per layer:
//   1) h = x @ W^T, stored interleaved  h[n][c][hd]  (c=0..63, hd=0..1)
//   2) si[n,hd], sj[n,hd] separable attention scores (dot with att halves)
//   3) Z[hd] = sum_e exp(leaky(si[dst]+sj[src]))   (global softmax denom;
//      max-shift skipped — logits bounded, mathematically identical)
//   4) one wave per dst node: acc += exp(leaky(..))/Z * h[src]; epilogue
//      fuses head-mean + bias (+relu) and writes out once.
// ---------------------------------------------------------------------------

// h[n, (col&63)*2 + (col>>6)] = sum_k x[n,k] * W[col,k],  col in [0,128)
template <int FIN>
__global__ __launch_bounds__(256) void gemm_nodes(
    const float* __restrict__ x, const float* __restrict__ W,
    float* __restrict__ h, int N) {
  const int NB = 64;
  __shared__ float xs[NB * FIN];
  int ntiles = (N + NB - 1) / NB;
  for (int tile = blockIdx.x; tile < ntiles; tile += gridDim.x) {
    int n0 = tile * NB;
    int cnt = min(NB, N - n0);
    __syncthreads();
    int nf4 = cnt * FIN / 4;
    const float4* xg4 = (const float4*)(x + (size_t)n0 * FIN);
    for (int i = threadIdx.x; i < nf4; i += 256) ((float4*)xs)[i] = xg4[i];
    __syncthreads();
    int col = threadIdx.x & 127;
    int perm = ((col & 63) << 1) | (col >> 6);  // interleave heads
    const float4* W4 = (const float4*)(W + (size_t)col * FIN);
    for (int nn = (threadIdx.x >> 7); nn < cnt; nn += 2) {
      const float4* xs4 = (const float4*)(xs + nn * FIN);
      float acc = 0.f;
#pragma unroll
      for (int k = 0; k < FIN / 4; ++k) {
        float4 w = W4[k];
        float4 xv = xs4[k];
        acc += w.x * xv.x + w.y * xv.y + w.z * xv.z + w.w * xv.w;
      }
      h[(size_t)(n0 + nn) * 128 + perm] = acc;
    }
  }
}

// one wave per node: si[n,hd], sj[n,hd] for both heads (h interleaved layout)
__global__ __launch_bounds__(256) void node_scores(
    const float* __restrict__ h, const float* __restrict__ att,
    float* __restrict__ si, float* __restrict__ sj, int N) {
  int lane = threadIdx.x & 63;
  int wid = (blockIdx.x * blockDim.x + threadIdx.x) >> 6;
  int nw = (gridDim.x * blockDim.x) >> 6;
  float a0i = att[lane], a0j = att[64 + lane];
  float a1i = att[128 + lane], a1j = att[192 + lane];
  for (int n = wid; n < N; n += nw) {
    float2 hv = ((const float2*)h)[(size_t)n * 64 + lane];
    float vi0 = hv.x * a0i, vj0 = hv.x * a0j;
    float vi1 = hv.y * a1i, vj1 = hv.y * a1j;
#pragma unroll
    for (int off = 32; off; off >>= 1) {
      vi0 += __shfl_down(vi0, off, 64);
      vj0 += __shfl_down(vj0, off, 64);
      vi1 += __shfl_down(vi1, off, 64);
      vj1 += __shfl_down(vj1, off, 64);
    }
    if (lane == 0) {
      si[n * 2] = vi0; si[n * 2 + 1] = vi1;
      sj[n * 2] = vj0; sj[n * 2 + 1] = vj1;
    }
  }
}

// Z[hd] = sum over edges of exp(leaky(si[dst]+sj[src]))
__global__ __launch_bounds__(256) void edge_exp_sum(
    const int* __restrict__ srcE, const int* __restrict__ dstE,
    const float* __restrict__ si, const float* __restrict__ sj,
    float* __restrict__ Z, int E, int Etot) {
  float s0 = 0.f, s1 = 0.f;
  int tid = blockIdx.x * blockDim.x + threadIdx.x;
  int stride = gridDim.x * blockDim.x;
  for (int e = tid; e < Etot; e += stride) {
    int s, d;
    if (e < E) { s = srcE[e]; d = dstE[e]; } else { s = d = e - E; }
    float a0 = si[d * 2] + sj[s * 2];
    float a1 = si[d * 2 + 1] + sj[s * 2 + 1];
    a0 = a0 >= 0.f ? a0 : 0.2f * a0;
    a1 = a1 >= 0.f ? a1 : 0.2f * a1;
    s0 += __expf(a0); s1 += __expf(a1);
  }
  __shared__ float r0[4], r1[4];
  int lane = threadIdx.x & 63, w = threadIdx.x >> 6;
#pragma unroll
  for (int off = 32; off; off >>= 1) {
    s0 += __shfl_down(s0, off, 64);
    s1 += __shfl_down(s1, off, 64);
  }
  if (lane == 0) { r0[w] = s0; r1[w] = s1; }
  __syncthreads();
  if (threadIdx.x == 0) {
    atomicAdd(&Z[0], r0[0] + r0[1] + r0[2] + r0[3]);
    atomicAdd(&Z[1], r1[0] + r1[1] + r1[2] + r1[3]);
  }
}

// -------------------- counting sort by dst --------------------
__global__ __launch_bounds__(256) void hist_dst(
    const int* __restrict__ dstE, int* __restrict__ deg, int E, int Etot) {
  int tid = blockIdx.x * blockDim.x + threadIdx.x;
  int stride = gridDim.x * blockDim.x;
  for (int e = tid; e < Etot; e += stride) {
    int d = (e < E) ? dstE[e] : e - E;
    atomicAdd(&deg[d], 1);
  }
}

// block b scans deg[b*1024 .. b*1024+1023] -> rowptr (local excl), bsum[b]=total
__global__ __launch_bounds__(256) void scan_blocks(
    const int* __restrict__ deg, int* __restrict__ rowptr,
    int* __restrict__ bsum, int N) {
  __shared__ int ts[256];
  int b = blockIdx.x, t = threadIdx.x;
  int base = b * 1024 + t * 4;
  int v[4];
#pragma unroll
  for (int j = 0; j < 4; ++j) v[j] = (base + j < N) ? deg[base + j] : 0;
  int tot = v[0] + v[1] + v[2] + v[3];
  ts[t] = tot;
  __syncthreads();
#pragma unroll
  for (int off = 1; off < 256; off <<= 1) {
    int x = (t >= off) ? ts[t - off] : 0;
    __syncthreads();
    ts[t] += x;
    __syncthreads();
  }
  int run = ts[t] - tot;  // exclusive prefix of this thread
#pragma unroll
  for (int j = 0; j < 4; ++j) {
    if (base + j < N) rowptr[base + j] = run;
    run += v[j];
  }
  if (t == 255) bsum[b] = ts[255];
}

__global__ __launch_bounds__(64) void scan_bsum(int* __restrict__ bsum, int nb) {
  __shared__ int ls[256];
  int t = threadIdx.x;
  for (int i = t; i < nb; i += 64) ls[i] = bsum[i];
  __syncthreads();
  if (t == 0) {
    int run = 0;
    for (int i = 0; i < nb; ++i) { int v = ls[i]; ls[i] = run; run += v; }
  }
  __syncthreads();
  for (int i = t; i < nb; i += 64) bsum[i] = ls[i];
}

__global__ __launch_bounds__(256) void scan_finish(
    int* __restrict__ rowptr, const int* __restrict__ bsum,
    int* __restrict__ cursor, int N, int Etot) {
  int tid = blockIdx.x * blockDim.x + threadIdx.x;
  int stride = gridDim.x * blockDim.x;
  for (int i = tid; i < N; i += stride) {
    int v = rowptr[i] + bsum[i >> 10];
    rowptr[i] = v;
    cursor[i] = v;
  }
  if (tid == 0) rowptr[N] = Etot;
}

__global__ __launch_bounds__(256) void scatter_edges(
    const int* __restrict__ srcE, const int* __restrict__ dstE,
    int* __restrict__ cursor, int* __restrict__ esrc, int E, int Etot) {
  int tid = blockIdx.x * blockDim.x + threadIdx.x;
  int stride = gridDim.x * blockDim.x;
  for (int e = tid; e < Etot; e += stride) {
    int s, d;
    if (e < E) { s = srcE[e]; d = dstE[e]; } else { s = d = e - E; }
    int pos = atomicAdd(&cursor[d], 1);
    esrc[pos] = s;
  }
}

// one wave per dst node: register accumulate, fused head-mean+bias(+relu)
__global__ __launch_bounds__(256) void csr_aggregate(
    const int* __restrict__ rowptr, const int* __restrict__ esrc,
    const float* __restrict__ h, const float* __restrict__ si,
    const float* __restrict__ sj, const float* __restrict__ Z,
    const float* __restrict__ bias, float* __restrict__ out,
    int N, int do_relu) {
  int lane = threadIdx.x & 63;
  int wid = (blockIdx.x * blockDim.x + threadIdx.x) >> 6;
  int nw = (gridDim.x * blockDim.x) >> 6;
  float z0 = 1.f / (Z[0] + 1e-10f);
  float z1 = 1.f / (Z[1] + 1e-10f);
  const float2* h2 = (const float2*)h;
  float bv = bias[lane];
  for (int n = wid; n < N; n += nw) {
    int beg = rowptr[n], end = rowptr[n + 1];
    float si0 = si[n * 2], si1 = si[n * 2 + 1];
    float acc0 = 0.f, acc1 = 0.f;
    for (int k = beg; k < end; ++k) {
      int s = esrc[k];
      float a0 = si0 + sj[s * 2];
      float a1 = si1 + sj[s * 2 + 1];
      a0 = a0 >= 0.f ? a0 : 0.2f * a0;
      a1 = a1 >= 0.f ? a1 : 0.2f * a1;
      float w0 = __expf(a0) * z0;
      float w1 = __expf(a1) * z1;
      float2 v = h2[(size_t)s * 64 + lane];
      acc0 += v.x * w0;
      acc1 += v.y * w1;
    }
    float r = 0.5f * (acc0 + acc1) + bv;
    if (do_relu) r = fmaxf(r, 0.f);
    out[(size_t)n * 64 + lane] = r;
  }
}

extern "C" void kernel_launch(void* const* d_in, const int* in_sizes, int n_in,
                              void* d_out, int out_size, void* d_ws, size_t ws_size,
                              hipStream_t stream) {
  const float* x    = (const float*)d_in[0];
  const int*   ei   = (const int*)d_in[1];   // [2, E] int32
  const float* W1   = (const float*)d_in[2];
  const float* att1 = (const float*)d_in[3];
  const float* b1   = (const float*)d_in[4];
  const float* W2   = (const float*)d_in[5];
  const float* att2 = (const float*)d_in[6];
  const float* b2   = (const float*)d_in[7];
  float* out = (float*)d_out;

  const int N = in_sizes[0] / 128;   // 50000
  const int E = in_sizes[1] / 2;     // 800000
  const int Etot = E + N;
  const int* srcE = ei;
  const int* dstE = ei + E;

  // workspace layout
  float* h    = (float*)d_ws;            // N*128
  float* si   = h + (size_t)N * 128;     // N*2
  float* sj   = si + (size_t)N * 2;      // N*2
  float* Z    = sj + (size_t)N * 2;      // 4
  float* x2   = Z + 4;                   // N*64
  int* rowptr = (int*)(x2 + (size_t)N * 64);  // N+1
  int* cursor = rowptr + (N + 1);        // N (also deg histogram)
  int* esrc   = cursor + N;              // Etot
  int* bsum   = esrc + Etot;             // up to 64

  dim3 blk(256);
  int nb = (N + 1023) / 1024;

  // ---------- CSR build (shared by both layers) ----------
  hipMemsetAsync(cursor, 0, (size_t)N * sizeof(int), stream);
  hist_dst<<<2048, blk, 0, stream>>>(dstE, cursor, E, Etot);
  scan_blocks<<<nb, blk, 0, stream>>>(cursor, rowptr, bsum, N);
  scan_bsum<<<1, 64, 0, stream>>>(bsum, nb);
  scan_finish<<<256, blk, 0, stream>>>(rowptr, bsum, cursor, N, Etot);
  scatter_edges<<<2048, blk, 0, stream>>>(srcE, dstE, cursor, esrc, E, Etot);

  // ---------------- layer 1 ----------------
  gemm_nodes<128><<<512, blk, 0, stream>>>(x, W1, h, N);
  node_scores<<<1024, blk, 0, stream>>>(h, att1, si, sj, N);
  hipMemsetAsync(Z, 0, 16, stream);
  edge_exp_sum<<<1024, blk, 0, stream>>>(srcE, dstE, si, sj, Z, E, Etot);
  csr_aggregate<<<4096, blk, 0, stream>>>(rowptr, esrc, h, si, sj, Z, b1, x2, N, 1);

  // ---------------- layer 2 ----------------
  gemm_nodes<64><<<512, blk, 0, stream>>>(x2, W2, h, N);
  node_scores<<<1024, blk, 0, stream>>>(h, att2, si, sj, N);
  hipMemsetAsync(Z, 0, 16, stream);
  edge_exp_sum<<<1024, blk, 0, stream>>>(srcE, dstE, si, sj, Z, E, Etot);
  csr_aggregate<<<4096, blk, 0, stream>>>(rowptr, esrc, h, si, sj, Z, b2, out, N, 0);
}

// Round 3
// 566.090 us; speedup vs baseline: 2.2172x; 1.1823x over previous
//
#include <hip/hip_runtime.h>
#include <hip/hip_bf16.h>
#include <math.h>

// ---------------------------------------------------------------------------
// GAT 2-layer forward, fp32, CSR-based aggregation (no f32 atomics).
//
// Once per call:  counting-sort edges by dst -> rowptr[N+1], esrc[Etot]
// Per layer:
//   1) h = x @ W^T, stored interleaved  h[n][c][hd]  (c=0..63, hd=0..1)
//      (register-tiled GEMM: 64 nodes x 128 cols / block, 8x4 acc / thread)
//   2) si[n,hd], sj[n,hd] separable attention scores
//   3) Z[hd] = sum_e exp(leaky(si[dst]+sj[src]))  (global softmax denom)
//   4) one wave per dst node: acc += exp(leaky(..))/Z * h[src]; fused
//      head-mean + bias (+relu) epilogue.
// ---------------------------------------------------------------------------

// Register-tiled GEMM. Block: 256 threads = 32 thread-cols x 8 thread-rows.
// Each thread: 8 nodes x 4 cols. K staged in chunks of 32.
template <int FIN>
__global__ __launch_bounds__(256) void gemm_tiled(
    const float* __restrict__ x, const float* __restrict__ W,
    float* __restrict__ h, int N) {
  __shared__ __align__(16) float xs[32][68];   // [k][node], pad 68
  __shared__ __align__(16) float ws[32][132];  // [k][col],  pad 132

  const int tid = threadIdx.x;
  const int tc = tid & 31;         // thread-col: cols tc*4 .. tc*4+3
  const int tr = tid >> 5;         // thread-row: nodes tr*8 .. tr*8+7
  const int n0 = blockIdx.x * 64;

  const float4* x4 = (const float4*)x;
  const float4* W4 = (const float4*)W;

  float acc[8][4];
#pragma unroll
  for (int i = 0; i < 8; ++i)
#pragma unroll
    for (int j = 0; j < 4; ++j) acc[i][j] = 0.f;

  for (int kc = 0; kc < FIN; kc += 32) {
    const int kc4 = kc >> 2;
    __syncthreads();
    // stage x tile: 64 nodes x 32 k = 512 float4, 2 per thread
#pragma unroll
    for (int r = 0; r < 2; ++r) {
      int i = tid + r * 256;
      int node = i >> 3, kq = i & 7;
      int gn = n0 + node;
      float4 v = make_float4(0.f, 0.f, 0.f, 0.f);
      if (gn < N) v = x4[(size_t)gn * (FIN / 4) + kc4 + kq];
      xs[kq * 4 + 0][node] = v.x;
      xs[kq * 4 + 1][node] = v.y;
      xs[kq * 4 + 2][node] = v.z;
      xs[kq * 4 + 3][node] = v.w;
    }
    // stage W tile: 128 cols x 32 k = 1024 float4, 4 per thread
#pragma unroll
    for (int r = 0; r < 4; ++r) {
      int i = tid + r * 256;
      int col = i >> 3, kq = i & 7;
      float4 v = W4[(size_t)col * (FIN / 4) + kc4 + kq];
      ws[kq * 4 + 0][col] = v.x;
      ws[kq * 4 + 1][col] = v.y;
      ws[kq * 4 + 2][col] = v.z;
      ws[kq * 4 + 3][col] = v.w;
    }
    __syncthreads();
#pragma unroll
    for (int k = 0; k < 32; ++k) {
      float4 wv = *(const float4*)&ws[k][tc * 4];
      float4 a0 = *(const float4*)&xs[k][tr * 8];
      float4 a1 = *(const float4*)&xs[k][tr * 8 + 4];
      float av[8] = {a0.x, a0.y, a0.z, a0.w, a1.x, a1.y, a1.z, a1.w};
      float wvv[4] = {wv.x, wv.y, wv.z, wv.w};
#pragma unroll
      for (int i = 0; i < 8; ++i)
#pragma unroll
        for (int j = 0; j < 4; ++j) acc[i][j] += av[i] * wvv[j];
    }
  }
  // epilogue: h[node][perm(col)], perm interleaves the two heads
#pragma unroll
  for (int i = 0; i < 8; ++i) {
    int node = n0 + tr * 8 + i;
    if (node >= N) break;
#pragma unroll
    for (int j = 0; j < 4; ++j) {
      int col = tc * 4 + j;
      int perm = ((col & 63) << 1) | (col >> 6);
      h[(size_t)node * 128 + perm] = acc[i][j];
    }
  }
}

// one wave per node: si[n,hd], sj[n,hd] for both heads (h interleaved layout)
__global__ __launch_bounds__(256) void node_scores(
    const float* __restrict__ h, const float* __restrict__ att,
    float* __restrict__ si, float* __restrict__ sj, int N) {
  int lane = threadIdx.x & 63;
  int wid = (blockIdx.x * blockDim.x + threadIdx.x) >> 6;
  int nw = (gridDim.x * blockDim.x) >> 6;
  float a0i = att[lane], a0j = att[64 + lane];
  float a1i = att[128 + lane], a1j = att[192 + lane];
  for (int n = wid; n < N; n += nw) {
    float2 hv = ((const float2*)h)[(size_t)n * 64 + lane];
    float vi0 = hv.x * a0i, vj0 = hv.x * a0j;
    float vi1 = hv.y * a1i, vj1 = hv.y * a1j;
#pragma unroll
    for (int off = 32; off; off >>= 1) {
      vi0 += __shfl_down(vi0, off, 64);
      vj0 += __shfl_down(vj0, off, 64);
      vi1 += __shfl_down(vi1, off, 64);
      vj1 += __shfl_down(vj1, off, 64);
    }
    if (lane == 0) {
      si[n * 2] = vi0; si[n * 2 + 1] = vi1;
      sj[n * 2] = vj0; sj[n * 2 + 1] = vj1;
    }
  }
}

// Z[hd] = sum over edges of exp(leaky(si[dst]+sj[src]))
__global__ __launch_bounds__(256) void edge_exp_sum(
    const int* __restrict__ srcE, const int* __restrict__ dstE,
    const float* __restrict__ si, const float* __restrict__ sj,
    float* __restrict__ Z, int E, int Etot) {
  float s0 = 0.f, s1 = 0.f;
  int tid = blockIdx.x * blockDim.x + threadIdx.x;
  int stride = gridDim.x * blockDim.x;
  for (int e = tid; e < Etot; e += stride) {
    int s, d;
    if (e < E) { s = srcE[e]; d = dstE[e]; } else { s = d = e - E; }
    float a0 = si[d * 2] + sj[s * 2];
    float a1 = si[d * 2 + 1] + sj[s * 2 + 1];
    a0 = a0 >= 0.f ? a0 : 0.2f * a0;
    a1 = a1 >= 0.f ? a1 : 0.2f * a1;
    s0 += __expf(a0); s1 += __expf(a1);
  }
  __shared__ float r0[4], r1[4];
  int lane = threadIdx.x & 63, w = threadIdx.x >> 6;
#pragma unroll
  for (int off = 32; off; off >>= 1) {
    s0 += __shfl_down(s0, off, 64);
    s1 += __shfl_down(s1, off, 64);
  }
  if (lane == 0) { r0[w] = s0; r1[w] = s1; }
  __syncthreads();
  if (threadIdx.x == 0) {
    atomicAdd(&Z[0], r0[0] + r0[1] + r0[2] + r0[3]);
    atomicAdd(&Z[1], r1[0] + r1[1] + r1[2] + r1[3]);
  }
}

// -------------------- counting sort by dst --------------------
__global__ __launch_bounds__(256) void hist_dst(
    const int* __restrict__ dstE, int* __restrict__ deg, int E, int Etot) {
  int tid = blockIdx.x * blockDim.x + threadIdx.x;
  int stride = gridDim.x * blockDim.x;
  for (int e = tid; e < Etot; e += stride) {
    int d = (e < E) ? dstE[e] : e - E;
    atomicAdd(&deg[d], 1);
  }
}

__global__ __launch_bounds__(256) void scan_blocks(
    const int* __restrict__ deg, int* __restrict__ rowptr,
    int* __restrict__ bsum, int N) {
  __shared__ int ts[256];
  int b = blockIdx.x, t = threadIdx.x;
  int base = b * 1024 + t * 4;
  int v[4];
#pragma unroll
  for (int j = 0; j < 4; ++j) v[j] = (base + j < N) ? deg[base + j] : 0;
  int tot = v[0] + v[1] + v[2] + v[3];
  ts[t] = tot;
  __syncthreads();
#pragma unroll
  for (int off = 1; off < 256; off <<= 1) {
    int x = (t >= off) ? ts[t - off] : 0;
    __syncthreads();
    ts[t] += x;
    __syncthreads();
  }
  int run = ts[t] - tot;
#pragma unroll
  for (int j = 0; j < 4; ++j) {
    if (base + j < N) rowptr[base + j] = run;
    run += v[j];
  }
  if (t == 255) bsum[b] = ts[255];
}

__global__ __launch_bounds__(64) void scan_bsum(int* __restrict__ bsum, int nb) {
  __shared__ int ls[256];
  int t = threadIdx.x;
  for (int i = t; i < nb; i += 64) ls[i] = bsum[i];
  __syncthreads();
  if (t == 0) {
    int run = 0;
    for (int i = 0; i < nb; ++i) { int v = ls[i]; ls[i] = run; run += v; }
  }
  __syncthreads();
  for (int i = t; i < nb; i += 64) bsum[i] = ls[i];
}

__global__ __launch_bounds__(256) void scan_finish(
    int* __restrict__ rowptr, const int* __restrict__ bsum,
    int* __restrict__ cursor, int N, int Etot) {
  int tid = blockIdx.x * blockDim.x + threadIdx.x;
  int stride = gridDim.x * blockDim.x;
  for (int i = tid; i < N; i += stride) {
    int v = rowptr[i] + bsum[i >> 10];
    rowptr[i] = v;
    cursor[i] = v;
  }
  if (tid == 0) rowptr[N] = Etot;
}

__global__ __launch_bounds__(256) void scatter_edges(
    const int* __restrict__ srcE, const int* __restrict__ dstE,
    int* __restrict__ cursor, int* __restrict__ esrc, int E, int Etot) {
  int tid = blockIdx.x * blockDim.x + threadIdx.x;
  int stride = gridDim.x * blockDim.x;
  for (int e = tid; e < Etot; e += stride) {
    int s, d;
    if (e < E) { s = srcE[e]; d = dstE[e]; } else { s = d = e - E; }
    int pos = atomicAdd(&cursor[d], 1);
    esrc[pos] = s;
  }
}

// one wave per dst node: register accumulate, fused head-mean+bias(+relu)
__global__ __launch_bounds__(256) void csr_aggregate(
    const int* __restrict__ rowptr, const int* __restrict__ esrc,
    const float* __restrict__ h, const float* __restrict__ si,
    const float* __restrict__ sj, const float* __restrict__ Z,
    const float* __restrict__ bias, float* __restrict__ out,
    int N, int do_relu) {
  int lane = threadIdx.x & 63;
  int wid = (blockIdx.x * blockDim.x + threadIdx.x) >> 6;
  int nw = (gridDim.x * blockDim.x) >> 6;
  float z0 = 1.f / (Z[0] + 1e-10f);
  float z1 = 1.f / (Z[1] + 1e-10f);
  const float2* h2 = (const float2*)h;
  float bv = bias[lane];
  for (int n = wid; n < N; n += nw) {
    int beg = rowptr[n], end = rowptr[n + 1];
    float si0 = si[n * 2], si1 = si[n * 2 + 1];
    float acc0 = 0.f, acc1 = 0.f;
    for (int k = beg; k < end; ++k) {
      int s = esrc[k];
      float a0 = si0 + sj[s * 2];
      float a1 = si1 + sj[s * 2 + 1];
      a0 = a0 >= 0.f ? a0 : 0.2f * a0;
      a1 = a1 >= 0.f ? a1 : 0.2f * a1;
      float w0 = __expf(a0) * z0;
      float w1 = __expf(a1) * z1;
      float2 v = h2[(size_t)s * 64 + lane];
      acc0 += v.x * w0;
      acc1 += v.y * w1;
    }
    float r = 0.5f * (acc0 + acc1) + bv;
    if (do_relu) r = fmaxf(r, 0.f);
    out[(size_t)n * 64 + lane] = r;
  }
}

extern "C" void kernel_launch(void* const* d_in, const int* in_sizes, int n_in,
                              void* d_out, int out_size, void* d_ws, size_t ws_size,
                              hipStream_t stream) {
  const float* x    = (const float*)d_in[0];
  const int*   ei   = (const int*)d_in[1];   // [2, E] int32
  const float* W1   = (const float*)d_in[2];
  const float* att1 = (const float*)d_in[3];
  const float* b1   = (const float*)d_in[4];
  const float* W2   = (const float*)d_in[5];
  const float* att2 = (const float*)d_in[6];
  const float* b2   = (const float*)d_in[7];
  float* out = (float*)d_out;

  const int N = in_sizes[0] / 128;   // 50000
  const int E = in_sizes[1] / 2;     // 800000
  const int Etot = E + N;
  const int* srcE = ei;
  const int* dstE = ei + E;

  // workspace layout
  float* h    = (float*)d_ws;            // N*128
  float* si   = h + (size_t)N * 128;     // N*2
  float* sj   = si + (size_t)N * 2;      // N*2
  float* Z    = sj + (size_t)N * 2;      // 4
  float* x2   = Z + 4;                   // N*64
  int* rowptr = (int*)(x2 + (size_t)N * 64);  // N+1
  int* cursor = rowptr + (N + 1);        // N (also deg histogram)
  int* esrc   = cursor + N;              // Etot
  int* bsum   = esrc + Etot;             // up to 64

  dim3 blk(256);
  int nb = (N + 1023) / 1024;
  int ntiles = (N + 63) / 64;

  // ---------- CSR build (shared by both layers) ----------
  hipMemsetAsync(cursor, 0, (size_t)N * sizeof(int), stream);
  hist_dst<<<2048, blk, 0, stream>>>(dstE, cursor, E, Etot);
  scan_blocks<<<nb, blk, 0, stream>>>(cursor, rowptr, bsum, N);
  scan_bsum<<<1, 64, 0, stream>>>(bsum, nb);
  scan_finish<<<256, blk, 0, stream>>>(rowptr, bsum, cursor, N, Etot);
  scatter_edges<<<2048, blk, 0, stream>>>(srcE, dstE, cursor, esrc, E, Etot);

  // ---------------- layer 1 ----------------
  gemm_tiled<128><<<ntiles, blk, 0, stream>>>(x, W1, h, N);
  node_scores<<<1024, blk, 0, stream>>>(h, att1, si, sj, N);
  hipMemsetAsync(Z, 0, 16, stream);
  edge_exp_sum<<<1024, blk, 0, stream>>>(srcE, dstE, si, sj, Z, E, Etot);
  csr_aggregate<<<4096, blk, 0, stream>>>(rowptr, esrc, h, si, sj, Z, b1, x2, N, 1);

  // ---------------- layer 2 ----------------
  gemm_tiled<64><<<ntiles, blk, 0, stream>>>(x2, W2, h, N);
  node_scores<<<1024, blk, 0, stream>>>(h, att2, si, sj, N);
  hipMemsetAsync(Z, 0, 16, stream);
  edge_exp_sum<<<1024, blk, 0, stream>>>(srcE, dstE, si, sj, Z, E, Etot);
  csr_aggregate<<<4096, blk, 0, stream>>>(rowptr, esrc, h, si, sj, Z, b2, out, N, 0);
}

// Round 4
// 385.385 us; speedup vs baseline: 3.2568x; 1.4689x over previous
//
#include <hip/hip_runtime.h>
#include <hip/hip_bf16.h>
#include <math.h>

// ---------------------------------------------------------------------------
// GAT 2-layer forward. CSR aggregation, bf16 gather table, exp hoisted.
//
// Once per call: counting-sort edges by dst -> rowptr[N+1], esrc[], erow[]
// Per layer:
//   1) gemm_fused: h = x@W^T  -> hq[n][c] = packed bf16x2 (head0 lo, head1 hi)
//      + fused si/sj attention scores (fp32, from fp32 accumulators)
//   2) csr_edge_weights: ew[k] = exp(leaky(si[dst]+sj[src])) per head (fp32),
//      Z[hd] += ew   (global softmax denominator; max-shift skipped — logits
//      bounded, mathematically identical)
//   3) csr_aggregate: one wave per dst node, acc += ew * hq[src]; epilogue
//      normalizes by Z, head-mean + bias (+relu), single write.
// ---------------------------------------------------------------------------

__device__ __forceinline__ unsigned f2bf(float x) {  // fp32 -> bf16 (RNE)
  unsigned u = __float_as_uint(x);
  return (u + 0x7fffu + ((u >> 16) & 1u)) >> 16;
}
__device__ __forceinline__ float bflo(unsigned p) { return __uint_as_float(p << 16); }
__device__ __forceinline__ float bfhi(unsigned p) { return __uint_as_float(p & 0xffff0000u); }

// Register-tiled GEMM + fused scores. Block: 256 = 32 thread-cols x 8 rows.
// Thread: 8 nodes x 4 cols (one head: tc<16 -> head0 ch tc*4.., tc>=16 -> head1).
template <int FIN>
__global__ __launch_bounds__(256) void gemm_fused(
    const float* __restrict__ x, const float* __restrict__ W,
    const float* __restrict__ att, unsigned* __restrict__ hq,
    float* __restrict__ si, float* __restrict__ sj, int N) {
  __shared__ __align__(16) float xs[32][68];
  __shared__ __align__(16) float ws[32][132];

  const int tid = threadIdx.x;
  const int tc = tid & 31;
  const int tr = tid >> 5;
  const int lane = tid & 63;
  const int n0 = blockIdx.x * 64;

  const float4* x4 = (const float4*)x;
  const float4* W4 = (const float4*)W;

  float acc[8][4];
#pragma unroll
  for (int i = 0; i < 8; ++i)
#pragma unroll
    for (int j = 0; j < 4; ++j) acc[i][j] = 0.f;

  for (int kc = 0; kc < FIN; kc += 32) {
    const int kc4 = kc >> 2;
    __syncthreads();
#pragma unroll
    for (int r = 0; r < 2; ++r) {
      int i = tid + r * 256;
      int node = i >> 3, kq = i & 7;
      int gn = n0 + node;
      float4 v = make_float4(0.f, 0.f, 0.f, 0.f);
      if (gn < N) v = x4[(size_t)gn * (FIN / 4) + kc4 + kq];
      xs[kq * 4 + 0][node] = v.x;
      xs[kq * 4 + 1][node] = v.y;
      xs[kq * 4 + 2][node] = v.z;
      xs[kq * 4 + 3][node] = v.w;
    }
#pragma unroll
    for (int r = 0; r < 4; ++r) {
      int i = tid + r * 256;
      int col = i >> 3, kq = i & 7;
      float4 v = W4[(size_t)col * (FIN / 4) + kc4 + kq];
      ws[kq * 4 + 0][col] = v.x;
      ws[kq * 4 + 1][col] = v.y;
      ws[kq * 4 + 2][col] = v.z;
      ws[kq * 4 + 3][col] = v.w;
    }
    __syncthreads();
#pragma unroll
    for (int k = 0; k < 32; ++k) {
      float4 wv = *(const float4*)&ws[k][tc * 4];
      float4 a0 = *(const float4*)&xs[k][tr * 8];
      float4 a1 = *(const float4*)&xs[k][tr * 8 + 4];
      float av[8] = {a0.x, a0.y, a0.z, a0.w, a1.x, a1.y, a1.z, a1.w};
      float wvv[4] = {wv.x, wv.y, wv.z, wv.w};
#pragma unroll
      for (int i = 0; i < 8; ++i)
#pragma unroll
        for (int j = 0; j < 4; ++j) acc[i][j] += av[i] * wvv[j];
    }
  }

  // ------- epilogue: pack bf16x2 h + fused attention scores -------
  const int hd = tc >> 4;          // head of my cols
  const int ch = (tc & 15) * 4;    // channel base
  float ai[4], aj[4];
#pragma unroll
  for (int j = 0; j < 4; ++j) {
    ai[j] = att[hd * 128 + ch + j];
    aj[j] = att[hd * 128 + 64 + ch + j];
  }
#pragma unroll
  for (int i = 0; i < 8; ++i) {
    int node = n0 + tr * 8 + i;
    float sip = 0.f, sjp = 0.f;
    unsigned w[4];
#pragma unroll
    for (int j = 0; j < 4; ++j) {
      float v = acc[i][j];
      sip += v * ai[j];
      sjp += v * aj[j];
      float other = __shfl_xor(v, 16, 64);  // partner head, same channel
      float h0 = (tc < 16) ? v : other;
      float h1 = (tc < 16) ? other : v;
      w[j] = f2bf(h0) | (f2bf(h1) << 16);
    }
    // segmented reduce over each 16-lane group (no wrap issues: lane L
    // result = sum of orig lanes L..L+15; we consume L in {0,16,32,48})
#pragma unroll
    for (int off = 8; off; off >>= 1) {
      sip += __shfl_down(sip, off, 64);
      sjp += __shfl_down(sjp, off, 64);
    }
    bool valid = node < N;
    if (valid && tc < 16) {
      *(uint4*)&hq[(size_t)node * 64 + ch] = make_uint4(w[0], w[1], w[2], w[3]);
    }
    if (valid && (lane & 15) == 0) {
      int hh = (lane >> 4) & 1;
      si[node * 2 + hh] = sip;
      sj[node * 2 + hh] = sjp;
    }
  }
}

// per CSR position: ew[k] = exp(leaky(si[dst]+sj[src])) both heads; Z += ew
__global__ __launch_bounds__(256) void csr_edge_weights(
    const int* __restrict__ esrc, const int* __restrict__ erow,
    const float2* __restrict__ si2, const float2* __restrict__ sj2,
    float2* __restrict__ ew2, float* __restrict__ Z, int Etot) {
  float z0 = 0.f, z1 = 0.f;
  int tid = blockIdx.x * blockDim.x + threadIdx.x;
  int stride = gridDim.x * blockDim.x;
  for (int e = tid; e < Etot; e += stride) {
    int s = esrc[e], d = erow[e];
    float2 siv = si2[d];
    float2 sjv = sj2[s];
    float a0 = siv.x + sjv.x;
    float a1 = siv.y + sjv.y;
    a0 = a0 >= 0.f ? a0 : 0.2f * a0;
    a1 = a1 >= 0.f ? a1 : 0.2f * a1;
    float e0 = __expf(a0), e1 = __expf(a1);
    ew2[e] = make_float2(e0, e1);
    z0 += e0; z1 += e1;
  }
  __shared__ float r0[4], r1[4];
  int lane = threadIdx.x & 63, w = threadIdx.x >> 6;
#pragma unroll
  for (int off = 32; off; off >>= 1) {
    z0 += __shfl_down(z0, off, 64);
    z1 += __shfl_down(z1, off, 64);
  }
  if (lane == 0) { r0[w] = z0; r1[w] = z1; }
  __syncthreads();
  if (threadIdx.x == 0) {
    atomicAdd(&Z[0], r0[0] + r0[1] + r0[2] + r0[3]);
    atomicAdd(&Z[1], r1[0] + r1[1] + r1[2] + r1[3]);
  }
}

// -------------------- counting sort by dst --------------------
__global__ __launch_bounds__(256) void hist_dst(
    const int* __restrict__ dstE, int* __restrict__ deg, int E, int Etot) {
  int tid = blockIdx.x * blockDim.x + threadIdx.x;
  int stride = gridDim.x * blockDim.x;
  for (int e = tid; e < Etot; e += stride) {
    int d = (e < E) ? dstE[e] : e - E;
    atomicAdd(&deg[d], 1);
  }
}

__global__ __launch_bounds__(256) void scan_blocks(
    const int* __restrict__ deg, int* __restrict__ rowptr,
    int* __restrict__ bsum, int N) {
  __shared__ int ts[256];
  int b = blockIdx.x, t = threadIdx.x;
  int base = b * 1024 + t * 4;
  int v[4];
#pragma unroll
  for (int j = 0; j < 4; ++j) v[j] = (base + j < N) ? deg[base + j] : 0;
  int tot = v[0] + v[1] + v[2] + v[3];
  ts[t] = tot;
  __syncthreads();
#pragma unroll
  for (int off = 1; off < 256; off <<= 1) {
    int x = (t >= off) ? ts[t - off] : 0;
    __syncthreads();
    ts[t] += x;
    __syncthreads();
  }
  int run = ts[t] - tot;
#pragma unroll
  for (int j = 0; j < 4; ++j) {
    if (base + j < N) rowptr[base + j] = run;
    run += v[j];
  }
  if (t == 255) bsum[b] = ts[255];
}

__global__ __launch_bounds__(64) void scan_bsum(int* __restrict__ bsum, int nb) {
  __shared__ int ls[256];
  int t = threadIdx.x;
  for (int i = t; i < nb; i += 64) ls[i] = bsum[i];
  __syncthreads();
  if (t == 0) {
    int run = 0;
    for (int i = 0; i < nb; ++i) { int v = ls[i]; ls[i] = run; run += v; }
  }
  __syncthreads();
  for (int i = t; i < nb; i += 64) bsum[i] = ls[i];
}

__global__ __launch_bounds__(256) void scan_finish(
    int* __restrict__ rowptr, const int* __restrict__ bsum,
    int* __restrict__ cursor, int N, int Etot) {
  int tid = blockIdx.x * blockDim.x + threadIdx.x;
  int stride = gridDim.x * blockDim.x;
  for (int i = tid; i < N; i += stride) {
    int v = rowptr[i] + bsum[i >> 10];
    rowptr[i] = v;
    cursor[i] = v;
  }
  if (tid == 0) rowptr[N] = Etot;
}

__global__ __launch_bounds__(256) void scatter_edges(
    const int* __restrict__ srcE, const int* __restrict__ dstE,
    int* __restrict__ cursor, int* __restrict__ esrc,
    int* __restrict__ erow, int E, int Etot) {
  int tid = blockIdx.x * blockDim.x + threadIdx.x;
  int stride = gridDim.x * blockDim.x;
  for (int e = tid; e < Etot; e += stride) {
    int s, d;
    if (e < E) { s = srcE[e]; d = dstE[e]; } else { s = d = e - E; }
    int pos = atomicAdd(&cursor[d], 1);
    esrc[pos] = s;
    erow[pos] = d;
  }
}

// one wave per dst node: acc += ew * hq[src] (bf16x2 gather), fused epilogue
__global__ __launch_bounds__(256) void csr_aggregate(
    const int* __restrict__ rowptr, const int* __restrict__ esrc,
    const unsigned* __restrict__ hq, const float2* __restrict__ ew2,
    const float* __restrict__ Z, const float* __restrict__ bias,
    float* __restrict__ out, int N, int do_relu) {
  int lane = threadIdx.x & 63;
  int wid = (blockIdx.x * blockDim.x + threadIdx.x) >> 6;
  int nw = (gridDim.x * blockDim.x) >> 6;
  float z0 = 1.f / (Z[0] + 1e-10f);
  float z1 = 1.f / (Z[1] + 1e-10f);
  float bv = bias[lane];
  for (int n = wid; n < N; n += nw) {
    int beg = rowptr[n], end = rowptr[n + 1];
    float acc0 = 0.f, acc1 = 0.f;
    int k = beg;
    for (; k + 4 <= end; k += 4) {
      int s0 = esrc[k], s1 = esrc[k + 1], s2 = esrc[k + 2], s3 = esrc[k + 3];
      float2 w0 = ew2[k], w1 = ew2[k + 1], w2 = ew2[k + 2], w3 = ew2[k + 3];
      unsigned p0 = hq[(size_t)s0 * 64 + lane];
      unsigned p1 = hq[(size_t)s1 * 64 + lane];
      unsigned p2 = hq[(size_t)s2 * 64 + lane];
      unsigned p3 = hq[(size_t)s3 * 64 + lane];
      acc0 += bflo(p0) * w0.x + bflo(p1) * w1.x + bflo(p2) * w2.x + bflo(p3) * w3.x;
      acc1 += bfhi(p0) * w0.y + bfhi(p1) * w1.y + bfhi(p2) * w2.y + bfhi(p3) * w3.y;
    }
    for (; k < end; ++k) {
      int s = esrc[k];
      float2 w = ew2[k];
      unsigned p = hq[(size_t)s * 64 + lane];
      acc0 += bflo(p) * w.x;
      acc1 += bfhi(p) * w.y;
    }
    float r = 0.5f * (acc0 * z0 + acc1 * z1) + bv;
    if (do_relu) r = fmaxf(r, 0.f);
    out[(size_t)n * 64 + lane] = r;
  }
}

extern "C" void kernel_launch(void* const* d_in, const int* in_sizes, int n_in,
                              void* d_out, int out_size, void* d_ws, size_t ws_size,
                              hipStream_t stream) {
  const float* x    = (const float*)d_in[0];
  const int*   ei   = (const int*)d_in[1];   // [2, E] int32
  const float* W1   = (const float*)d_in[2];
  const float* att1 = (const float*)d_in[3];
  const float* b1   = (const float*)d_in[4];
  const float* W2   = (const float*)d_in[5];
  const float* att2 = (const float*)d_in[6];
  const float* b2   = (const float*)d_in[7];
  float* out = (float*)d_out;

  const int N = in_sizes[0] / 128;   // 50000
  const int E = in_sizes[1] / 2;     // 800000
  const int Etot = E + N;
  const int* srcE = ei;
  const int* dstE = ei + E;

  // workspace layout (all segments 16B-aligned)
  unsigned* hq = (unsigned*)d_ws;                 // N*64 packed bf16x2
  float* si    = (float*)(hq + (size_t)N * 64);   // N*2
  float* sj    = si + (size_t)N * 2;              // N*2
  float* Z     = sj + (size_t)N * 2;              // 4
  float* x2    = Z + 4;                           // N*64
  float2* ew2  = (float2*)(x2 + (size_t)N * 64);  // Etot
  int* rowptr  = (int*)(ew2 + Etot);              // N+1
  int* cursor  = rowptr + (N + 1);                // N (deg histogram too)
  int* esrc    = cursor + N;                      // Etot
  int* erow    = esrc + Etot;                     // Etot
  int* bsum    = erow + Etot;                     // up to 64

  dim3 blk(256);
  int nb = (N + 1023) / 1024;
  int ntiles = (N + 63) / 64;

  // ---------- CSR build (shared by both layers) ----------
  hipMemsetAsync(cursor, 0, (size_t)N * sizeof(int), stream);
  hist_dst<<<2048, blk, 0, stream>>>(dstE, cursor, E, Etot);
  scan_blocks<<<nb, blk, 0, stream>>>(cursor, rowptr, bsum, N);
  scan_bsum<<<1, 64, 0, stream>>>(bsum, nb);
  scan_finish<<<256, blk, 0, stream>>>(rowptr, bsum, cursor, N, Etot);
  scatter_edges<<<2048, blk, 0, stream>>>(srcE, dstE, cursor, esrc, erow, E, Etot);

  // ---------------- layer 1 ----------------
  gemm_fused<128><<<ntiles, blk, 0, stream>>>(x, W1, att1, hq, si, sj, N);
  hipMemsetAsync(Z, 0, 16, stream);
  csr_edge_weights<<<1024, blk, 0, stream>>>(esrc, erow, (const float2*)si,
                                             (const float2*)sj, ew2, Z, Etot);
  csr_aggregate<<<4096, blk, 0, stream>>>(rowptr, esrc, hq, ew2, Z, b1, x2, N, 1);

  // ---------------- layer 2 ----------------
  gemm_fused<64><<<ntiles, blk, 0, stream>>>(x2, W2, att2, hq, si, sj, N);
  hipMemsetAsync(Z, 0, 16, stream);
  csr_edge_weights<<<1024, blk, 0, stream>>>(esrc, erow, (const float2*)si,
                                             (const float2*)sj, ew2, Z, Etot);
  csr_aggregate<<<4096, blk, 0, stream>>>(rowptr, esrc, hq, ew2, Z, b2, out, N, 0);
}

// Round 5
// 342.740 us; speedup vs baseline: 3.6620x; 1.1244x over previous
//
#include <hip/hip_runtime.h>
#include <hip/hip_bf16.h>
#include <math.h>

// ---------------------------------------------------------------------------
// GAT 2-layer forward. CSR aggregation, bf16 gather table, exp hoisted.
//
// Once per call: counting-sort edges by dst -> rowptr[N+1], esrc[]
// Per layer:
//   1) gemm_fused: h = x@W^T -> hq[n][c] packed bf16x2 (head0 lo, head1 hi)
//      + fused si/sj attention scores (fp32)
//   2) csr_edge_weights (node-parallel): ew[k] = exp(leaky(si[n]+sj[src]))
//      per head, Z[hd] += ew  (global softmax denom; max-shift skipped —
//      logits bounded, mathematically identical)
//   3) csr_aggregate: one wave per dst node (scalarized CSR walk),
//      acc += ew * hq[src]; epilogue normalizes by Z, head-mean+bias(+relu).
// ---------------------------------------------------------------------------

__device__ __forceinline__ unsigned f2bf(float x) {  // fp32 -> bf16 (RNE)
  unsigned u = __float_as_uint(x);
  return (u + 0x7fffu + ((u >> 16) & 1u)) >> 16;
}
__device__ __forceinline__ float bflo(unsigned p) { return __uint_as_float(p << 16); }
__device__ __forceinline__ float bfhi(unsigned p) { return __uint_as_float(p & 0xffff0000u); }

// Register-tiled GEMM + fused scores. Block: 256 = 32 thread-cols x 8 rows.
template <int FIN>
__global__ __launch_bounds__(256) void gemm_fused(
    const float* __restrict__ x, const float* __restrict__ W,
    const float* __restrict__ att, unsigned* __restrict__ hq,
    float* __restrict__ si, float* __restrict__ sj, int N) {
  __shared__ __align__(16) float xs[32][68];
  __shared__ __align__(16) float ws[32][132];

  const int tid = threadIdx.x;
  const int tc = tid & 31;
  const int tr = tid >> 5;
  const int lane = tid & 63;
  const int n0 = blockIdx.x * 64;

  const float4* x4 = (const float4*)x;
  const float4* W4 = (const float4*)W;

  float acc[8][4];
#pragma unroll
  for (int i = 0; i < 8; ++i)
#pragma unroll
    for (int j = 0; j < 4; ++j) acc[i][j] = 0.f;

  for (int kc = 0; kc < FIN; kc += 32) {
    const int kc4 = kc >> 2;
    __syncthreads();
#pragma unroll
    for (int r = 0; r < 2; ++r) {
      int i = tid + r * 256;
      int node = i >> 3, kq = i & 7;
      int gn = n0 + node;
      float4 v = make_float4(0.f, 0.f, 0.f, 0.f);
      if (gn < N) v = x4[(size_t)gn * (FIN / 4) + kc4 + kq];
      xs[kq * 4 + 0][node] = v.x;
      xs[kq * 4 + 1][node] = v.y;
      xs[kq * 4 + 2][node] = v.z;
      xs[kq * 4 + 3][node] = v.w;
    }
#pragma unroll
    for (int r = 0; r < 4; ++r) {
      int i = tid + r * 256;
      int col = i >> 3, kq = i & 7;
      float4 v = W4[(size_t)col * (FIN / 4) + kc4 + kq];
      ws[kq * 4 + 0][col] = v.x;
      ws[kq * 4 + 1][col] = v.y;
      ws[kq * 4 + 2][col] = v.z;
      ws[kq * 4 + 3][col] = v.w;
    }
    __syncthreads();
#pragma unroll
    for (int k = 0; k < 32; ++k) {
      float4 wv = *(const float4*)&ws[k][tc * 4];
      float4 a0 = *(const float4*)&xs[k][tr * 8];
      float4 a1 = *(const float4*)&xs[k][tr * 8 + 4];
      float av[8] = {a0.x, a0.y, a0.z, a0.w, a1.x, a1.y, a1.z, a1.w};
      float wvv[4] = {wv.x, wv.y, wv.z, wv.w};
#pragma unroll
      for (int i = 0; i < 8; ++i)
#pragma unroll
        for (int j = 0; j < 4; ++j) acc[i][j] += av[i] * wvv[j];
    }
  }

  // ------- epilogue: pack bf16x2 h + fused attention scores -------
  const int hd = tc >> 4;
  const int ch = (tc & 15) * 4;
  float ai[4], aj[4];
#pragma unroll
  for (int j = 0; j < 4; ++j) {
    ai[j] = att[hd * 128 + ch + j];
    aj[j] = att[hd * 128 + 64 + ch + j];
  }
#pragma unroll
  for (int i = 0; i < 8; ++i) {
    int node = n0 + tr * 8 + i;
    float sip = 0.f, sjp = 0.f;
    unsigned w[4];
#pragma unroll
    for (int j = 0; j < 4; ++j) {
      float v = acc[i][j];
      sip += v * ai[j];
      sjp += v * aj[j];
      float other = __shfl_xor(v, 16, 64);  // partner head, same channel
      float h0 = (tc < 16) ? v : other;
      float h1 = (tc < 16) ? other : v;
      w[j] = f2bf(h0) | (f2bf(h1) << 16);
    }
#pragma unroll
    for (int off = 8; off; off >>= 1) {
      sip += __shfl_down(sip, off, 64);
      sjp += __shfl_down(sjp, off, 64);
    }
    bool valid = node < N;
    if (valid && tc < 16) {
      *(uint4*)&hq[(size_t)node * 64 + ch] = make_uint4(w[0], w[1], w[2], w[3]);
    }
    if (valid && (lane & 15) == 0) {
      int hh = (lane >> 4) & 1;
      si[node * 2 + hh] = sip;
      sj[node * 2 + hh] = sjp;
    }
  }
}

// node-parallel: thread n walks rowptr[n]..rowptr[n+1], writes ew2, sums Z
__global__ __launch_bounds__(256) void csr_edge_weights(
    const int* __restrict__ rowptr, const int* __restrict__ esrc,
    const float2* __restrict__ si2, const float2* __restrict__ sj2,
    float2* __restrict__ ew2, float* __restrict__ Z, int N) {
  float z0 = 0.f, z1 = 0.f;
  int tid = blockIdx.x * blockDim.x + threadIdx.x;
  int stride = gridDim.x * blockDim.x;
  for (int n = tid; n < N; n += stride) {
    int beg = rowptr[n], end = rowptr[n + 1];
    float2 siv = si2[n];
    for (int k = beg; k < end; ++k) {
      int s = esrc[k];
      float2 sjv = sj2[s];
      float a0 = siv.x + sjv.x;
      float a1 = siv.y + sjv.y;
      a0 = a0 >= 0.f ? a0 : 0.2f * a0;
      a1 = a1 >= 0.f ? a1 : 0.2f * a1;
      float e0 = __expf(a0), e1 = __expf(a1);
      ew2[k] = make_float2(e0, e1);
      z0 += e0; z1 += e1;
    }
  }
  __shared__ float r0[4], r1[4];
  int lane = threadIdx.x & 63, w = threadIdx.x >> 6;
#pragma unroll
  for (int off = 32; off; off >>= 1) {
    z0 += __shfl_down(z0, off, 64);
    z1 += __shfl_down(z1, off, 64);
  }
  if (lane == 0) { r0[w] = z0; r1[w] = z1; }
  __syncthreads();
  if (threadIdx.x == 0) {
    atomicAdd(&Z[0], r0[0] + r0[1] + r0[2] + r0[3]);
    atomicAdd(&Z[1], r1[0] + r1[1] + r1[2] + r1[3]);
  }
}

// -------------------- counting sort by dst --------------------
__global__ __launch_bounds__(256) void hist_dst(
    const int* __restrict__ dstE, int* __restrict__ deg, int E, int Etot) {
  int tid = blockIdx.x * blockDim.x + threadIdx.x;
  int stride = gridDim.x * blockDim.x;
  for (int e = tid; e < Etot; e += stride) {
    int d = (e < E) ? dstE[e] : e - E;
    atomicAdd(&deg[d], 1);
  }
}

__global__ __launch_bounds__(256) void scan_blocks(
    const int* __restrict__ deg, int* __restrict__ rowptr,
    int* __restrict__ bsum, int N) {
  __shared__ int ts[256];
  int b = blockIdx.x, t = threadIdx.x;
  int base = b * 1024 + t * 4;
  int v[4];
#pragma unroll
  for (int j = 0; j < 4; ++j) v[j] = (base + j < N) ? deg[base + j] : 0;
  int tot = v[0] + v[1] + v[2] + v[3];
  ts[t] = tot;
  __syncthreads();
#pragma unroll
  for (int off = 1; off < 256; off <<= 1) {
    int x = (t >= off) ? ts[t - off] : 0;
    __syncthreads();
    ts[t] += x;
    __syncthreads();
  }
  int run = ts[t] - tot;
#pragma unroll
  for (int j = 0; j < 4; ++j) {
    if (base + j < N) rowptr[base + j] = run;
    run += v[j];
  }
  if (t == 255) bsum[b] = ts[255];
}

__global__ __launch_bounds__(64) void scan_bsum(int* __restrict__ bsum, int nb) {
  __shared__ int ls[256];
  int t = threadIdx.x;
  for (int i = t; i < nb; i += 64) ls[i] = bsum[i];
  __syncthreads();
  if (t == 0) {
    int run = 0;
    for (int i = 0; i < nb; ++i) { int v = ls[i]; ls[i] = run; run += v; }
  }
  __syncthreads();
  for (int i = t; i < nb; i += 64) bsum[i] = ls[i];
}

__global__ __launch_bounds__(256) void scan_finish(
    int* __restrict__ rowptr, const int* __restrict__ bsum,
    int* __restrict__ cursor, int N, int Etot) {
  int tid = blockIdx.x * blockDim.x + threadIdx.x;
  int stride = gridDim.x * blockDim.x;
  for (int i = tid; i < N; i += stride) {
    int v = rowptr[i] + bsum[i >> 10];
    rowptr[i] = v;
    cursor[i] = v;
  }
  if (tid == 0) rowptr[N] = Etot;
}

__global__ __launch_bounds__(256) void scatter_edges(
    const int* __restrict__ srcE, const int* __restrict__ dstE,
    int* __restrict__ cursor, int* __restrict__ esrc, int E, int Etot) {
  int tid = blockIdx.x * blockDim.x + threadIdx.x;
  int stride = gridDim.x * blockDim.x;
  for (int e = tid; e < Etot; e += stride) {
    int s, d;
    if (e < E) { s = srcE[e]; d = dstE[e]; } else { s = d = e - E; }
    int pos = atomicAdd(&cursor[d], 1);
    esrc[pos] = s;
  }
}

// one wave per dst node (scalarized): acc += ew * hq[src], fused epilogue
__global__ __launch_bounds__(256) void csr_aggregate(
    const int* __restrict__ rowptr, const int* __restrict__ esrc,
    const unsigned* __restrict__ hq, const float2* __restrict__ ew2,
    const float* __restrict__ Z, const float* __restrict__ bias,
    float* __restrict__ out, int N, int do_relu) {
  int lane = threadIdx.x & 63;
  int wid = (blockIdx.x * blockDim.x + threadIdx.x) >> 6;
  int nw = (gridDim.x * blockDim.x) >> 6;
  float z0 = 1.f / (Z[0] + 1e-10f);
  float z1 = 1.f / (Z[1] + 1e-10f);
  float bv = bias[lane];
  for (int n0 = wid; n0 < N; n0 += nw) {
    // n is wave-uniform; force SGPR so rowptr/esrc/ew2 use scalar loads
    int n = __builtin_amdgcn_readfirstlane(n0);
    int beg = rowptr[n], end = rowptr[n + 1];
    float acc0 = 0.f, acc1 = 0.f;
    int k = beg;
    for (; k + 4 <= end; k += 4) {
      int s0 = esrc[k], s1 = esrc[k + 1], s2 = esrc[k + 2], s3 = esrc[k + 3];
      float2 w0 = ew2[k], w1 = ew2[k + 1], w2 = ew2[k + 2], w3 = ew2[k + 3];
      unsigned p0 = hq[(size_t)s0 * 64 + lane];
      unsigned p1 = hq[(size_t)s1 * 64 + lane];
      unsigned p2 = hq[(size_t)s2 * 64 + lane];
      unsigned p3 = hq[(size_t)s3 * 64 + lane];
      acc0 += bflo(p0) * w0.x + bflo(p1) * w1.x + bflo(p2) * w2.x + bflo(p3) * w3.x;
      acc1 += bfhi(p0) * w0.y + bfhi(p1) * w1.y + bfhi(p2) * w2.y + bfhi(p3) * w3.y;
    }
    for (; k < end; ++k) {
      int s = esrc[k];
      float2 w = ew2[k];
      unsigned p = hq[(size_t)s * 64 + lane];
      acc0 += bflo(p) * w.x;
      acc1 += bfhi(p) * w.y;
    }
    float r = 0.5f * (acc0 * z0 + acc1 * z1) + bv;
    if (do_relu) r = fmaxf(r, 0.f);
    out[(size_t)n * 64 + lane] = r;
  }
}

extern "C" void kernel_launch(void* const* d_in, const int* in_sizes, int n_in,
                              void* d_out, int out_size, void* d_ws, size_t ws_size,
                              hipStream_t stream) {
  const float* x    = (const float*)d_in[0];
  const int*   ei   = (const int*)d_in[1];   // [2, E] int32
  const float* W1   = (const float*)d_in[2];
  const float* att1 = (const float*)d_in[3];
  const float* b1   = (const float*)d_in[4];
  const float* W2   = (const float*)d_in[5];
  const float* att2 = (const float*)d_in[6];
  const float* b2   = (const float*)d_in[7];
  float* out = (float*)d_out;

  const int N = in_sizes[0] / 128;   // 50000
  const int E = in_sizes[1] / 2;     // 800000
  const int Etot = E + N;
  const int* srcE = ei;
  const int* dstE = ei + E;

  // workspace layout (all segments 16B-aligned)
  unsigned* hq = (unsigned*)d_ws;                 // N*64 packed bf16x2
  float* si    = (float*)(hq + (size_t)N * 64);   // N*2
  float* sj    = si + (size_t)N * 2;              // N*2
  float* Z     = sj + (size_t)N * 2;              // 4
  float* x2    = Z + 4;                           // N*64
  float2* ew2  = (float2*)(x2 + (size_t)N * 64);  // Etot
  int* rowptr  = (int*)(ew2 + Etot);              // N+1
  int* cursor  = rowptr + (N + 1);                // N (deg histogram too)
  int* esrc    = cursor + N;                      // Etot
  int* bsum    = esrc + Etot;                     // up to 64

  dim3 blk(256);
  int nb = (N + 1023) / 1024;
  int ntiles = (N + 63) / 64;

  // ---------- CSR build (shared by both layers) ----------
  hipMemsetAsync(cursor, 0, (size_t)N * sizeof(int), stream);
  hist_dst<<<2048, blk, 0, stream>>>(dstE, cursor, E, Etot);
  scan_blocks<<<nb, blk, 0, stream>>>(cursor, rowptr, bsum, N);
  scan_bsum<<<1, 64, 0, stream>>>(bsum, nb);
  scan_finish<<<256, blk, 0, stream>>>(rowptr, bsum, cursor, N, Etot);
  scatter_edges<<<2048, blk, 0, stream>>>(srcE, dstE, cursor, esrc, E, Etot);

  // ---------------- layer 1 ----------------
  gemm_fused<128><<<ntiles, blk, 0, stream>>>(x, W1, att1, hq, si, sj, N);
  hipMemsetAsync(Z, 0, 16, stream);
  csr_edge_weights<<<256, blk, 0, stream>>>(rowptr, esrc, (const float2*)si,
                                            (const float2*)sj, ew2, Z, N);
  csr_aggregate<<<4096, blk, 0, stream>>>(rowptr, esrc, hq, ew2, Z, b1, x2, N, 1);

  // ---------------- layer 2 ----------------
  gemm_fused<64><<<ntiles, blk, 0, stream>>>(x2, W2, att2, hq, si, sj, N);
  hipMemsetAsync(Z, 0, 16, stream);
  csr_edge_weights<<<256, blk, 0, stream>>>(rowptr, esrc, (const float2*)si,
                                            (const float2*)sj, ew2, Z, N);
  csr_aggregate<<<4096, blk, 0, stream>>>(rowptr, esrc, hq, ew2, Z, b2, out, N, 0);
}

// Round 6
// 332.943 us; speedup vs baseline: 3.7698x; 1.0294x over previous
//
#include <hip/hip_runtime.h>
#include <hip/hip_bf16.h>
#include <math.h>

// ---------------------------------------------------------------------------
// GAT 2-layer forward. CSR aggregation, bf16 gather table, exp hoisted.
//
// Once per call: counting-sort edges by dst -> rowptr[N+1], esrc[]
//   scatter is dst-partitioned (8 ranges, XCD-affine via blockIdx%8) so the
//   random cursor atomics + esrc stores stay resident in ONE L2 slice.
// Per layer:
//   1) gemm_fused: h = x@W^T -> hq[n][c] packed bf16x2 + fused si/sj scores
//   2) csr_edge_weights (node-parallel): ew[k], Z[hd] (global softmax denom;
//      max-shift skipped — logits bounded, mathematically identical)
//   3) csr_aggregate: one wave per dst node (scalarized CSR walk),
//      acc += ew * hq[src]; epilogue normalizes by Z, head-mean+bias(+relu).
// ---------------------------------------------------------------------------

__device__ __forceinline__ unsigned f2bf(float x) {  // fp32 -> bf16 (RNE)
  unsigned u = __float_as_uint(x);
  return (u + 0x7fffu + ((u >> 16) & 1u)) >> 16;
}
__device__ __forceinline__ float bflo(unsigned p) { return __uint_as_float(p << 16); }
__device__ __forceinline__ float bfhi(unsigned p) { return __uint_as_float(p & 0xffff0000u); }

// Register-tiled GEMM + fused scores. Block: 256 = 32 thread-cols x 8 rows.
template <int FIN>
__global__ __launch_bounds__(256) void gemm_fused(
    const float* __restrict__ x, const float* __restrict__ W,
    const float* __restrict__ att, unsigned* __restrict__ hq,
    float* __restrict__ si, float* __restrict__ sj, int N) {
  __shared__ __align__(16) float xs[32][68];
  __shared__ __align__(16) float ws[32][132];

  const int tid = threadIdx.x;
  const int tc = tid & 31;
  const int tr = tid >> 5;
  const int lane = tid & 63;
  const int n0 = blockIdx.x * 64;

  const float4* x4 = (const float4*)x;
  const float4* W4 = (const float4*)W;

  float acc[8][4];
#pragma unroll
  for (int i = 0; i < 8; ++i)
#pragma unroll
    for (int j = 0; j < 4; ++j) acc[i][j] = 0.f;

  for (int kc = 0; kc < FIN; kc += 32) {
    const int kc4 = kc >> 2;
    __syncthreads();
#pragma unroll
    for (int r = 0; r < 2; ++r) {
      int i = tid + r * 256;
      int node = i >> 3, kq = i & 7;
      int gn = n0 + node;
      float4 v = make_float4(0.f, 0.f, 0.f, 0.f);
      if (gn < N) v = x4[(size_t)gn * (FIN / 4) + kc4 + kq];
      xs[kq * 4 + 0][node] = v.x;
      xs[kq * 4 + 1][node] = v.y;
      xs[kq * 4 + 2][node] = v.z;
      xs[kq * 4 + 3][node] = v.w;
    }
#pragma unroll
    for (int r = 0; r < 4; ++r) {
      int i = tid + r * 256;
      int col = i >> 3, kq = i & 7;
      float4 v = W4[(size_t)col * (FIN / 4) + kc4 + kq];
      ws[kq * 4 + 0][col] = v.x;
      ws[kq * 4 + 1][col] = v.y;
      ws[kq * 4 + 2][col] = v.z;
      ws[kq * 4 + 3][col] = v.w;
    }
    __syncthreads();
#pragma unroll
    for (int k = 0; k < 32; ++k) {
      float4 wv = *(const float4*)&ws[k][tc * 4];
      float4 a0 = *(const float4*)&xs[k][tr * 8];
      float4 a1 = *(const float4*)&xs[k][tr * 8 + 4];
      float av[8] = {a0.x, a0.y, a0.z, a0.w, a1.x, a1.y, a1.z, a1.w};
      float wvv[4] = {wv.x, wv.y, wv.z, wv.w};
#pragma unroll
      for (int i = 0; i < 8; ++i)
#pragma unroll
        for (int j = 0; j < 4; ++j) acc[i][j] += av[i] * wvv[j];
    }
  }

  // ------- epilogue: pack bf16x2 h + fused attention scores -------
  const int hd = tc >> 4;
  const int ch = (tc & 15) * 4;
  float ai[4], aj[4];
#pragma unroll
  for (int j = 0; j < 4; ++j) {
    ai[j] = att[hd * 128 + ch + j];
    aj[j] = att[hd * 128 + 64 + ch + j];
  }
#pragma unroll
  for (int i = 0; i < 8; ++i) {
    int node = n0 + tr * 8 + i;
    float sip = 0.f, sjp = 0.f;
    unsigned w[4];
#pragma unroll
    for (int j = 0; j < 4; ++j) {
      float v = acc[i][j];
      sip += v * ai[j];
      sjp += v * aj[j];
      float other = __shfl_xor(v, 16, 64);  // partner head, same channel
      float h0 = (tc < 16) ? v : other;
      float h1 = (tc < 16) ? other : v;
      w[j] = f2bf(h0) | (f2bf(h1) << 16);
    }
#pragma unroll
    for (int off = 8; off; off >>= 1) {
      sip += __shfl_down(sip, off, 64);
      sjp += __shfl_down(sjp, off, 64);
    }
    bool valid = node < N;
    if (valid && tc < 16) {
      *(uint4*)&hq[(size_t)node * 64 + ch] = make_uint4(w[0], w[1], w[2], w[3]);
    }
    if (valid && (lane & 15) == 0) {
      int hh = (lane >> 4) & 1;
      si[node * 2 + hh] = sip;
      sj[node * 2 + hh] = sjp;
    }
  }
}

// node-parallel: thread n walks rowptr[n]..rowptr[n+1], writes ew2, sums Z
__global__ __launch_bounds__(256) void csr_edge_weights(
    const int* __restrict__ rowptr, const int* __restrict__ esrc,
    const float2* __restrict__ si2, const float2* __restrict__ sj2,
    float2* __restrict__ ew2, float* __restrict__ Z, int N) {
  float z0 = 0.f, z1 = 0.f;
  int tid = blockIdx.x * blockDim.x + threadIdx.x;
  int stride = gridDim.x * blockDim.x;
  for (int n = tid; n < N; n += stride) {
    int beg = rowptr[n], end = rowptr[n + 1];
    float2 siv = si2[n];
    for (int k = beg; k < end; ++k) {
      int s = esrc[k];
      float2 sjv = sj2[s];
      float a0 = siv.x + sjv.x;
      float a1 = siv.y + sjv.y;
      a0 = a0 >= 0.f ? a0 : 0.2f * a0;
      a1 = a1 >= 0.f ? a1 : 0.2f * a1;
      float e0 = __expf(a0), e1 = __expf(a1);
      ew2[k] = make_float2(e0, e1);
      z0 += e0; z1 += e1;
    }
  }
  __shared__ float r0[4], r1[4];
  int lane = threadIdx.x & 63, w = threadIdx.x >> 6;
#pragma unroll
  for (int off = 32; off; off >>= 1) {
    z0 += __shfl_down(z0, off, 64);
    z1 += __shfl_down(z1, off, 64);
  }
  if (lane == 0) { r0[w] = z0; r1[w] = z1; }
  __syncthreads();
  if (threadIdx.x == 0) {
    atomicAdd(&Z[0], r0[0] + r0[1] + r0[2] + r0[3]);
    atomicAdd(&Z[1], r1[0] + r1[1] + r1[2] + r1[3]);
  }
}

// -------------------- counting sort by dst --------------------
__global__ __launch_bounds__(256) void hist_dst(
    const int* __restrict__ dstE, int* __restrict__ deg, int E, int Etot) {
  int tid = blockIdx.x * blockDim.x + threadIdx.x;
  int stride = gridDim.x * blockDim.x;
  for (int e = tid; e < Etot; e += stride) {
    int d = (e < E) ? dstE[e] : e - E;
    atomicAdd(&deg[d], 1);
  }
}

__global__ __launch_bounds__(256) void scan_blocks(
    const int* __restrict__ deg, int* __restrict__ rowptr,
    int* __restrict__ bsum, int N) {
  __shared__ int ts[256];
  int b = blockIdx.x, t = threadIdx.x;
  int base = b * 1024 + t * 4;
  int v[4];
#pragma unroll
  for (int j = 0; j < 4; ++j) v[j] = (base + j < N) ? deg[base + j] : 0;
  int tot = v[0] + v[1] + v[2] + v[3];
  ts[t] = tot;
  __syncthreads();
#pragma unroll
  for (int off = 1; off < 256; off <<= 1) {
    int x = (t >= off) ? ts[t - off] : 0;
    __syncthreads();
    ts[t] += x;
    __syncthreads();
  }
  int run = ts[t] - tot;
#pragma unroll
  for (int j = 0; j < 4; ++j) {
    if (base + j < N) rowptr[base + j] = run;
    run += v[j];
  }
  if (t == 255) bsum[b] = ts[255];
}

__global__ __launch_bounds__(64) void scan_bsum(int* __restrict__ bsum, int nb) {
  __shared__ int ls[256];
  int t = threadIdx.x;
  for (int i = t; i < nb; i += 64) ls[i] = bsum[i];
  __syncthreads();
  if (t == 0) {
    int run = 0;
    for (int i = 0; i < nb; ++i) { int v = ls[i]; ls[i] = run; run += v; }
  }
  __syncthreads();
  for (int i = t; i < nb; i += 64) bsum[i] = ls[i];
}

__global__ __launch_bounds__(256) void scan_finish(
    int* __restrict__ rowptr, const int* __restrict__ bsum,
    int* __restrict__ cursor, int N, int Etot) {
  int tid = blockIdx.x * blockDim.x + threadIdx.x;
  int stride = gridDim.x * blockDim.x;
  for (int i = tid; i < N; i += stride) {
    int v = rowptr[i] + bsum[i >> 10];
    rowptr[i] = v;
    cursor[i] = v;
  }
  if (tid == 0) rowptr[N] = Etot;
}

// dst-partitioned scatter: partition p = blockIdx%8 handles dst in
// [p*step, (p+1)*step). Under round-robin block->XCD dispatch all blocks of a
// partition land on one XCD, so cursor atomics + esrc stores stay in one L2.
// (Mapping is a locality heuristic only — correctness never depends on it.)
__global__ __launch_bounds__(256) void scatter_part(
    const int* __restrict__ srcE, const int* __restrict__ dstE,
    int* __restrict__ cursor, int* __restrict__ esrc,
    int E, int Etot, int step) {
  const int p = blockIdx.x & 7;
  const int sub = blockIdx.x >> 3;
  const int nsub = gridDim.x >> 3;
  const int lo = p * step;
  const int hi = lo + step;
  int stride = nsub * 256;
  for (int e = sub * 256 + threadIdx.x; e < Etot; e += stride) {
    int d = (e < E) ? dstE[e] : e - E;
    if (d >= lo && d < hi) {
      int s = (e < E) ? srcE[e] : d;
      int pos = atomicAdd(&cursor[d], 1);
      esrc[pos] = s;
    }
  }
}

// one wave per dst node (scalarized): acc += ew * hq[src], fused epilogue
__global__ __launch_bounds__(256) void csr_aggregate(
    const int* __restrict__ rowptr, const int* __restrict__ esrc,
    const unsigned* __restrict__ hq, const float2* __restrict__ ew2,
    const float* __restrict__ Z, const float* __restrict__ bias,
    float* __restrict__ out, int N, int do_relu) {
  int lane = threadIdx.x & 63;
  int wid = (blockIdx.x * blockDim.x + threadIdx.x) >> 6;
  int nw = (gridDim.x * blockDim.x) >> 6;
  float z0 = 1.f / (Z[0] + 1e-10f);
  float z1 = 1.f / (Z[1] + 1e-10f);
  float bv = bias[lane];
  for (int n0 = wid; n0 < N; n0 += nw) {
    int n = __builtin_amdgcn_readfirstlane(n0);
    int beg = rowptr[n], end = rowptr[n + 1];
    float acc0 = 0.f, acc1 = 0.f;
    int k = beg;
    for (; k + 4 <= end; k += 4) {
      int s0 = esrc[k], s1 = esrc[k + 1], s2 = esrc[k + 2], s3 = esrc[k + 3];
      float2 w0 = ew2[k], w1 = ew2[k + 1], w2 = ew2[k + 2], w3 = ew2[k + 3];
      unsigned p0 = hq[(size_t)s0 * 64 + lane];
      unsigned p1 = hq[(size_t)s1 * 64 + lane];
      unsigned p2 = hq[(size_t)s2 * 64 + lane];
      unsigned p3 = hq[(size_t)s3 * 64 + lane];
      acc0 += bflo(p0) * w0.x + bflo(p1) * w1.x + bflo(p2) * w2.x + bflo(p3) * w3.x;
      acc1 += bfhi(p0) * w0.y + bfhi(p1) * w1.y + bfhi(p2) * w2.y + bfhi(p3) * w3.y;
    }
    for (; k < end; ++k) {
      int s = esrc[k];
      float2 w = ew2[k];
      unsigned p = hq[(size_t)s * 64 + lane];
      acc0 += bflo(p) * w.x;
      acc1 += bfhi(p) * w.y;
    }
    float r = 0.5f * (acc0 * z0 + acc1 * z1) + bv;
    if (do_relu) r = fmaxf(r, 0.f);
    out[(size_t)n * 64 + lane] = r;
  }
}

extern "C" void kernel_launch(void* const* d_in, const int* in_sizes, int n_in,
                              void* d_out, int out_size, void* d_ws, size_t ws_size,
                              hipStream_t stream) {
  const float* x    = (const float*)d_in[0];
  const int*   ei   = (const int*)d_in[1];   // [2, E] int32
  const float* W1   = (const float*)d_in[2];
  const float* att1 = (const float*)d_in[3];
  const float* b1   = (const float*)d_in[4];
  const float* W2   = (const float*)d_in[5];
  const float* att2 = (const float*)d_in[6];
  const float* b2   = (const float*)d_in[7];
  float* out = (float*)d_out;

  const int N = in_sizes[0] / 128;   // 50000
  const int E = in_sizes[1] / 2;     // 800000
  const int Etot = E + N;
  const int* srcE = ei;
  const int* dstE = ei + E;

  // workspace layout (all segments 16B-aligned)
  unsigned* hq = (unsigned*)d_ws;                 // N*64 packed bf16x2
  float* si    = (float*)(hq + (size_t)N * 64);   // N*2
  float* sj    = si + (size_t)N * 2;              // N*2
  float* Z     = sj + (size_t)N * 2;              // 4
  float* x2    = Z + 4;                           // N*64
  float2* ew2  = (float2*)(x2 + (size_t)N * 64);  // Etot
  int* rowptr  = (int*)(ew2 + Etot);              // N+1
  int* cursor  = rowptr + (N + 1);                // N (deg histogram too)
  int* esrc    = cursor + N;                      // Etot
  int* bsum    = esrc + Etot;                     // up to 64

  dim3 blk(256);
  int nb = (N + 1023) / 1024;
  int ntiles = (N + 63) / 64;
  int step = (N + 7) / 8;

  // ---------- CSR build (shared by both layers) ----------
  hipMemsetAsync(cursor, 0, (size_t)N * sizeof(int), stream);
  hist_dst<<<2048, blk, 0, stream>>>(dstE, cursor, E, Etot);
  scan_blocks<<<nb, blk, 0, stream>>>(cursor, rowptr, bsum, N);
  scan_bsum<<<1, 64, 0, stream>>>(bsum, nb);
  scan_finish<<<256, blk, 0, stream>>>(rowptr, bsum, cursor, N, Etot);
  scatter_part<<<2048, blk, 0, stream>>>(srcE, dstE, cursor, esrc, E, Etot, step);

  // ---------------- layer 1 ----------------
  gemm_fused<128><<<ntiles, blk, 0, stream>>>(x, W1, att1, hq, si, sj, N);
  hipMemsetAsync(Z, 0, 16, stream);
  csr_edge_weights<<<256, blk, 0, stream>>>(rowptr, esrc, (const float2*)si,
                                            (const float2*)sj, ew2, Z, N);
  csr_aggregate<<<4096, blk, 0, stream>>>(rowptr, esrc, hq, ew2, Z, b1, x2, N, 1);

  // ---------------- layer 2 ----------------
  gemm_fused<64><<<ntiles, blk, 0, stream>>>(x2, W2, att2, hq, si, sj, N);
  hipMemsetAsync(Z, 0, 16, stream);
  csr_edge_weights<<<256, blk, 0, stream>>>(rowptr, esrc, (const float2*)si,
                                            (const float2*)sj, ew2, Z, N);
  csr_aggregate<<<4096, blk, 0, stream>>>(rowptr, esrc, hq, ew2, Z, b2, out, N, 0);
}